// Round 1
// baseline (353.853 us; speedup 1.0000x reference)
//
#include <hip/hip_runtime.h>
#include <hip/hip_bf16.h>

#define NN 16384
#define NE 524288
#define FIN 256
#define HH1 64
#define HH2 32

typedef __attribute__((ext_vector_type(8))) short bf16x8;
typedef __attribute__((ext_vector_type(4))) float f32x4;

// ---------------- utility ----------------
__global__ __launch_bounds__(256) void zero_ints(int* __restrict__ p, int n) {
  int i = blockIdx.x * 256 + threadIdx.x;
  if (i < n) p[i] = 0;
}

// ---------------- H0 = x @ W1  ([16384,256] @ [256,64]) ----------------
__global__ __launch_bounds__(256) void gemm_xw1(const float* __restrict__ x,
                                                const float* __restrict__ W1,
                                                float* __restrict__ H0) {
  __shared__ float xs[64][65];
  __shared__ float ws[64][65];
  const int t = threadIdx.x;
  const int row0 = blockIdx.x * 64;
  const int tr = t >> 4, tc = t & 15;
  float acc[4][4] = {};
  for (int kc = 0; kc < FIN; kc += 64) {
#pragma unroll
    for (int i = 0; i < 4; ++i) {
      int slot = t + i * 256;                // 1024 float4 slots
      int r = slot >> 4, c4 = (slot & 15) * 4;
      float4 v = *reinterpret_cast<const float4*>(&x[(size_t)(row0 + r) * FIN + kc + c4]);
      xs[r][c4 + 0] = v.x; xs[r][c4 + 1] = v.y; xs[r][c4 + 2] = v.z; xs[r][c4 + 3] = v.w;
      float4 wv = *reinterpret_cast<const float4*>(&W1[(size_t)(kc + r) * HH1 + c4]);
      ws[r][c4 + 0] = wv.x; ws[r][c4 + 1] = wv.y; ws[r][c4 + 2] = wv.z; ws[r][c4 + 3] = wv.w;
    }
    __syncthreads();
#pragma unroll
    for (int k = 0; k < 64; ++k) {
      float a[4], b[4];
#pragma unroll
      for (int i = 0; i < 4; ++i) a[i] = xs[tr * 4 + i][k];
#pragma unroll
      for (int j = 0; j < 4; ++j) b[j] = ws[k][tc * 4 + j];
#pragma unroll
      for (int i = 0; i < 4; ++i)
#pragma unroll
        for (int j = 0; j < 4; ++j) acc[i][j] += a[i] * b[j];
    }
    __syncthreads();
  }
#pragma unroll
  for (int i = 0; i < 4; ++i) {
    float4 o; o.x = acc[i][0]; o.y = acc[i][1]; o.z = acc[i][2]; o.w = acc[i][3];
    *reinterpret_cast<float4*>(&H0[(size_t)(row0 + tr * 4 + i) * HH1 + tc * 4]) = o;
  }
}

// ---------------- counting sort of edges by src ----------------
__global__ __launch_bounds__(256) void hist_src(const int* __restrict__ src,
                                                int* __restrict__ cnt) {
  int e = blockIdx.x * 256 + threadIdx.x;
  if (e < NE) atomicAdd(&cnt[src[e]], 1);
}

__global__ __launch_bounds__(256) void scan_offsets(const int* __restrict__ cnt,
                                                    int* __restrict__ off,
                                                    int* __restrict__ cur) {
  __shared__ int sums[256];
  const int t = threadIdx.x;
  const int base = t * 64;
  int s = 0;
  for (int i = 0; i < 64; ++i) s += cnt[base + i];
  sums[t] = s;
  __syncthreads();
  if (t == 0) {
    int run = 0;
    for (int i = 0; i < 256; ++i) { int v = sums[i]; sums[i] = run; run += v; }
  }
  __syncthreads();
  int run = sums[t];
  for (int i = 0; i < 64; ++i) {
    off[base + i] = run;
    cur[base + i] = run;
    run += cnt[base + i];
  }
  if (t == 255) off[NN] = run;   // == NE
}

__global__ __launch_bounds__(256) void scatter_edges(const int* __restrict__ src,
                                                     const int* __restrict__ dst,
                                                     const float* __restrict__ w,
                                                     int* __restrict__ cur,
                                                     int* __restrict__ sdst,
                                                     float* __restrict__ sw) {
  int e = blockIdx.x * 256 + threadIdx.x;
  if (e < NE) {
    int s = src[e];
    int p = atomicAdd(&cur[s], 1);
    sdst[p] = dst[e];
    sw[p] = w[e];
  }
}

// ---------------- SPMM: one wave per node, 64 features ----------------
__global__ __launch_bounds__(256) void spmm64(const int* __restrict__ off,
                                              const int* __restrict__ sdst,
                                              const float* __restrict__ sw,
                                              const float* __restrict__ Hin,
                                              float* __restrict__ Hout) {
  const int node = blockIdx.x * 4 + (threadIdx.x >> 6);
  const int lane = threadIdx.x & 63;
  const int beg = off[node], end = off[node + 1];
  float acc = 0.f;
  int e = beg;
  for (; e + 1 < end; e += 2) {
    int d0 = sdst[e], d1 = sdst[e + 1];
    float w0 = sw[e], w1 = sw[e + 1];
    acc += w0 * Hin[(size_t)d0 * 64 + lane];
    acc += w1 * Hin[(size_t)d1 * 64 + lane];
  }
  if (e < end) acc += sw[e] * Hin[(size_t)sdst[e] * 64 + lane];
  Hout[(size_t)node * 64 + lane] = acc;
}

// second SPMM writes z_mean / z_log_std straight into d_out
__global__ __launch_bounds__(256) void spmm_out(const int* __restrict__ off,
                                                const int* __restrict__ sdst,
                                                const float* __restrict__ sw,
                                                const float* __restrict__ G,
                                                float* __restrict__ zmean,
                                                float* __restrict__ zlog) {
  const int node = blockIdx.x * 4 + (threadIdx.x >> 6);
  const int lane = threadIdx.x & 63;
  const int beg = off[node], end = off[node + 1];
  float acc = 0.f;
  int e = beg;
  for (; e + 1 < end; e += 2) {
    int d0 = sdst[e], d1 = sdst[e + 1];
    float w0 = sw[e], w1 = sw[e + 1];
    acc += w0 * G[(size_t)d0 * 64 + lane];
    acc += w1 * G[(size_t)d1 * 64 + lane];
  }
  if (e < end) acc += sw[e] * G[(size_t)sdst[e] * 64 + lane];
  if (lane < 32) zmean[(size_t)node * 32 + lane] = acc;
  else           zlog[(size_t)node * 32 + (lane - 32)] = acc;
}

// ---------------- G = [h@W2 | h@W3]  ([16384,64] @ [64,32] x2) ----------------
__global__ __launch_bounds__(256) void gemm_h_w23(const float* __restrict__ h1,
                                                  const float* __restrict__ W2,
                                                  const float* __restrict__ W3,
                                                  float* __restrict__ G) {
  __shared__ float wsh[64][64];   // cols 0-31 = W2, 32-63 = W3
  __shared__ float hrow[4][64];
  const int t = threadIdx.x;
  for (int i = t; i < 64 * 32; i += 256) {
    int k = i >> 5, c = i & 31;
    wsh[k][c]      = W2[i];
    wsh[k][c + 32] = W3[i];
  }
  const int node0 = blockIdx.x * 4;
  const int wv = t >> 6, lane = t & 63;
  for (int i = t; i < 4 * 64; i += 256)
    hrow[i >> 6][i & 63] = h1[(size_t)(node0 + (i >> 6)) * 64 + (i & 63)];
  __syncthreads();
  float acc = 0.f;
#pragma unroll
  for (int k = 0; k < 64; ++k) acc += hrow[wv][k] * wsh[k][lane];
  G[(size_t)(node0 + wv) * 64 + lane] = acc;
}

// ---------------- zt = ((z*R)@M)*R  -> bf16 ----------------
__global__ __launch_bounds__(256) void zt_kernel(const float* __restrict__ zmean,
                                                 const float* __restrict__ R,
                                                 const float* __restrict__ M,
                                                 __hip_bfloat16* __restrict__ ztb) {
  __shared__ float Ms[32][33];
  __shared__ float zr[8][32];
  const int t = threadIdx.x;
  for (int i = t; i < 1024; i += 256) Ms[i >> 5][i & 31] = M[i];
  const int node0 = blockIdx.x * 8;
  const int sub = t >> 5, lane = t & 31;
  zr[sub][lane] = zmean[(size_t)(node0 + sub) * 32 + lane] * R[lane];
  __syncthreads();
  float acc = 0.f;
#pragma unroll
  for (int k = 0; k < 32; ++k) acc += zr[sub][k] * Ms[k][lane];
  ztb[(size_t)(node0 + sub) * 32 + lane] = __float2bfloat16(acc * R[lane]);
}

// ---------------- adj = zt @ zt^T  (bf16 MFMA, fp32 out) ----------------
__global__ __launch_bounds__(256) void adj_mfma(const __hip_bfloat16* __restrict__ ztb,
                                                float* __restrict__ adj) {
  const int wave = threadIdx.x >> 6;
  const int lane = threadIdx.x & 63;
  const int rbase = blockIdx.y * 64 + wave * 16;
  const int cbase = blockIdx.x * 64;
  const int l15 = lane & 15;
  const int kblk = lane >> 4;                  // 0..3
  const short* zs = reinterpret_cast<const short*>(ztb);

  // A fragment: lane l holds A[l&15][(l>>4)*8 + i] = zt[rbase+(l&15)][...]
  bf16x8 a = *reinterpret_cast<const bf16x8*>(&zs[(size_t)(rbase + l15) * 32 + kblk * 8]);

  f32x4 d[4];
#pragma unroll
  for (int tcol = 0; tcol < 4; ++tcol) {
    // B fragment: lane l holds B[(l>>4)*8+i][l&15] = zt[cbase+tcol*16+(l&15)][...]
    bf16x8 b = *reinterpret_cast<const bf16x8*>(
        &zs[(size_t)(cbase + tcol * 16 + l15) * 32 + kblk * 8]);
    f32x4 c = {0.f, 0.f, 0.f, 0.f};
    d[tcol] = __builtin_amdgcn_mfma_f32_16x16x32_bf16(a, b, c, 0, 0, 0);
  }

  const int row0 = rbase + kblk * 4;           // C/D: col=lane&15, row=(lane>>4)*4+reg
#pragma unroll
  for (int tcol = 0; tcol < 4; ++tcol) {
    const size_t col = (size_t)(cbase + tcol * 16 + l15);
#pragma unroll
    for (int r = 0; r < 4; ++r) {
      adj[(size_t)(row0 + r) * NN + col] = d[tcol][r];
    }
  }
}

// ---------------- launcher ----------------
extern "C" void kernel_launch(void* const* d_in, const int* in_sizes, int n_in,
                              void* d_out, int out_size, void* d_ws, size_t ws_size,
                              hipStream_t stream) {
  (void)in_sizes; (void)n_in; (void)out_size; (void)ws_size;

  const float* x   = (const float*)d_in[0];
  const float* ew  = (const float*)d_in[1];
  const float* W1  = (const float*)d_in[2];
  const float* W2  = (const float*)d_in[3];
  const float* W3  = (const float*)d_in[4];
  const float* R   = (const float*)d_in[5];
  const float* M   = (const float*)d_in[6];
  const int* esrc  = (const int*)d_in[7];
  const int* edst  = (const int*)d_in[8];

  float* adj_out   = (float*)d_out;
  float* zmean_out = adj_out + (size_t)NN * NN;
  float* zlog_out  = zmean_out + (size_t)NN * HH2;

  char* p = (char*)d_ws;
  float* H0 = (float*)p;                 p += (size_t)NN * HH1 * 4;   // 4 MB
  float* h1 = (float*)p;                 p += (size_t)NN * HH1 * 4;   // 4 MB
  float* G  = (float*)p;                 p += (size_t)NN * HH1 * 4;   // 4 MB
  __hip_bfloat16* ztb = (__hip_bfloat16*)p; p += (size_t)NN * HH2 * 2; // 1 MB
  int* cnt  = (int*)p;                   p += (size_t)NN * 4;
  int* off  = (int*)p;                   p += (size_t)(NN + 4) * 4;
  int* cur  = (int*)p;                   p += (size_t)NN * 4;
  int* sdst = (int*)p;                   p += (size_t)NE * 4;         // 2 MB
  float* sw = (float*)p;                 p += (size_t)NE * 4;         // 2 MB

  zero_ints<<<NN / 256, 256, 0, stream>>>(cnt, NN);
  gemm_xw1<<<NN / 64, 256, 0, stream>>>(x, W1, H0);
  hist_src<<<NE / 256, 256, 0, stream>>>(esrc, cnt);
  scan_offsets<<<1, 256, 0, stream>>>(cnt, off, cur);
  scatter_edges<<<NE / 256, 256, 0, stream>>>(esrc, edst, ew, cur, sdst, sw);
  spmm64<<<NN / 4, 256, 0, stream>>>(off, sdst, sw, H0, h1);
  gemm_h_w23<<<NN / 4, 256, 0, stream>>>(h1, W2, W3, G);
  spmm_out<<<NN / 4, 256, 0, stream>>>(off, sdst, sw, G, zmean_out, zlog_out);
  zt_kernel<<<NN / 8, 256, 0, stream>>>(zmean_out, R, M, ztb);

  dim3 g(NN / 64, NN / 64, 1);
  adj_mfma<<<g, 256, 0, stream>>>(ztb, adj_out);
}